// Round 3
// baseline (2376.172 us; speedup 1.0000x reference)
//
#include <hip/hip_runtime.h>
#include <hip/hip_bf16.h>

#define NU 50000
#define NI 50000
#define NEDGE 150000
#define CC 128
#define HH 8
#define HCC 1024

// ---------------- kernel A: fold attention vectors ----------------
// v[mat][cin][h] = sum_c W[cin, h*128+c] * a[h, c]
__global__ void fold_kernel(const float* __restrict__ W0, const float* __restrict__ a0,
                            const float* __restrict__ W1, const float* __restrict__ a1,
                            const float* __restrict__ W2, const float* __restrict__ a2,
                            const float* __restrict__ W3, const float* __restrict__ a3,
                            float* __restrict__ v4) {
    int gid = blockIdx.x * blockDim.x + threadIdx.x;   // 4096 total
    if (gid >= 4096) return;
    int mat = gid >> 10;
    int rem = gid & 1023;
    int cin = rem >> 3;
    int h   = rem & 7;
    const float* W = (mat == 0) ? W0 : (mat == 1) ? W1 : (mat == 2) ? W2 : W3;
    const float* a = (mat == 0) ? a0 : (mat == 1) ? a1 : (mat == 2) ? a2 : a3;
    const float* wrow = W + (size_t)cin * HCC + h * CC;
    const float* arow = a + h * CC;
    float acc = 0.f;
    #pragma unroll 8
    for (int c = 0; c < CC; ++c) acc += wrow[c] * arow[c];
    v4[gid] = acc;   // layout [mat][cin*8+h]
}

// ---------------- kernel B: attention logits per node ----------------
// cfg 0: al_s_ui = x_u @ v0 ; cfg 1: al_d_ui = x_i @ v1
// cfg 2: al_s_iu = x_i @ v2 ; cfg 3: al_d_iu = x_u @ v3
__global__ __launch_bounds__(256) void al_kernel(const float* __restrict__ xu, const float* __restrict__ xi,
                          const float* __restrict__ v4,
                          float* __restrict__ al0, float* __restrict__ al1,
                          float* __restrict__ al2, float* __restrict__ al3) {
    __shared__ float xs[32][132];
    __shared__ float vs[1024];
    int cfg = blockIdx.y;
    const float* x = (cfg == 0 || cfg == 3) ? xu : xi;
    int n = (cfg == 0 || cfg == 3) ? NU : NI;
    float* out = (cfg == 0) ? al0 : (cfg == 1) ? al1 : (cfg == 2) ? al2 : al3;
    const float* v = v4 + cfg * 1024;
    int n0 = blockIdx.x * 32;
    int tid = threadIdx.x;
    #pragma unroll
    for (int r = 0; r < 4; ++r) vs[tid + r * 256] = v[tid + r * 256];
    #pragma unroll
    for (int r = 0; r < 4; ++r) {
        int q = tid + r * 256;            // float4 id, 1024 total
        int row = q >> 5;
        int c4 = (q & 31) << 2;
        float4 f = make_float4(0.f, 0.f, 0.f, 0.f);
        if (n0 + row < n) f = *(const float4*)&x[(size_t)(n0 + row) * CC + c4];
        xs[row][c4] = f.x; xs[row][c4 + 1] = f.y; xs[row][c4 + 2] = f.z; xs[row][c4 + 3] = f.w;
    }
    __syncthreads();
    int nl = tid >> 3, h = tid & 7;
    if (n0 + nl < n) {
        float acc = 0.f;
        #pragma unroll 8
        for (int c = 0; c < CC; ++c) acc += xs[nl][c] * vs[c * 8 + h];
        out[(size_t)(n0 + nl) * 8 + h] = acc;
    }
}

// ---------------- kernel C: hs = x @ Wsrc  ([rows,128] @ [128,1024]) ----------------
__global__ __launch_bounds__(256) void gemm_hs_kernel(const float* __restrict__ x, const float* __restrict__ W,
                               float* __restrict__ hs, int M) {
    __shared__ float At[128][68];   // A^T tile: At[k][m]
    __shared__ float Bs[128][68];   // B tile:  Bs[k][n] (64 used)
    int tid = threadIdx.x;
    int m0 = blockIdx.x * 64;
    int n0 = blockIdx.y * 64;
    #pragma unroll
    for (int r = 0; r < 8; ++r) {
        int q = r * 256 + tid;            // 2048 float4 (A tile)
        int row = q >> 5;                 // 0..63
        int k4 = (q & 31) << 2;
        float4 f = make_float4(0.f, 0.f, 0.f, 0.f);
        if (m0 + row < M) f = *(const float4*)&x[(size_t)(m0 + row) * CC + k4];
        At[k4][row] = f.x; At[k4 + 1][row] = f.y; At[k4 + 2][row] = f.z; At[k4 + 3][row] = f.w;
    }
    #pragma unroll
    for (int r = 0; r < 8; ++r) {
        int q = r * 256 + tid;            // 2048 float4 (B tile)
        int kb = q >> 4;                  // 0..127
        int c4 = (q & 15) << 2;
        float4 f = *(const float4*)&W[(size_t)kb * HCC + n0 + c4];
        *(float4*)&Bs[kb][c4] = f;
    }
    __syncthreads();
    int tx = tid & 15, ty = tid >> 4;
    float acc[4][4];
    #pragma unroll
    for (int i = 0; i < 4; ++i)
        #pragma unroll
        for (int j = 0; j < 4; ++j) acc[i][j] = 0.f;
    #pragma unroll 4
    for (int k = 0; k < 128; ++k) {
        float4 a = *(float4*)&At[k][ty << 2];
        float4 b = *(float4*)&Bs[k][tx << 2];
        acc[0][0] += a.x * b.x; acc[0][1] += a.x * b.y; acc[0][2] += a.x * b.z; acc[0][3] += a.x * b.w;
        acc[1][0] += a.y * b.x; acc[1][1] += a.y * b.y; acc[1][2] += a.y * b.z; acc[1][3] += a.y * b.w;
        acc[2][0] += a.z * b.x; acc[2][1] += a.z * b.y; acc[2][2] += a.z * b.z; acc[2][3] += a.z * b.w;
        acc[3][0] += a.w * b.x; acc[3][1] += a.w * b.y; acc[3][2] += a.w * b.z; acc[3][3] += a.w * b.w;
    }
    #pragma unroll
    for (int i = 0; i < 4; ++i) {
        int m = m0 + (ty << 2) + i;
        if (m < M) {
            float4 o = make_float4(acc[i][0], acc[i][1], acc[i][2], acc[i][3]);
            *(float4*)&hs[(size_t)m * HCC + n0 + (tx << 2)] = o;
        }
    }
}

// ---------------- kernel D: per-edge exp(leakyrelu(logit)) + segment sums ----------------
__global__ void edge_exp_kernel(const int* __restrict__ ei, const float* __restrict__ al_s,
                                const float* __restrict__ al_d, float* __restrict__ eb,
                                float* __restrict__ s) {
    int e = blockIdx.x * 256 + threadIdx.x;
    if (e >= NEDGE) return;
    int src = ei[e];
    int dst = ei[NEDGE + e];
    float4 s01 = *(const float4*)&al_s[(size_t)src * 8];
    float4 s23 = *(const float4*)&al_s[(size_t)src * 8 + 4];
    float4 d01 = *(const float4*)&al_d[(size_t)dst * 8];
    float4 d23 = *(const float4*)&al_d[(size_t)dst * 8 + 4];
    float lv[8] = { s01.x + d01.x, s01.y + d01.y, s01.z + d01.z, s01.w + d01.w,
                    s23.x + d23.x, s23.y + d23.y, s23.z + d23.z, s23.w + d23.w };
    float ev[8];
    #pragma unroll
    for (int h = 0; h < 8; ++h) {
        float t = lv[h];
        t = (t > 0.f) ? t : 0.2f * t;      // leaky_relu slope 0.2
        ev[h] = expf(t);                    // no max-shift needed (|logit| small)
    }
    *(float4*)&eb[(size_t)e * 8]     = make_float4(ev[0], ev[1], ev[2], ev[3]);
    *(float4*)&eb[(size_t)e * 8 + 4] = make_float4(ev[4], ev[5], ev[6], ev[7]);
    #pragma unroll
    for (int h = 0; h < 8; ++h) atomicAdd(&s[(size_t)dst * 8 + h], ev[h]);
}

// ---------------- kernel E: scatter messages (head-mean + softmax-normalize folded) ----------------
// Processes only edges with src in [c0, c1); hs holds rows [c0, c1).
__global__ __launch_bounds__(256) void scatter_kernel(const int* __restrict__ ei, const float* __restrict__ eb,
                               const float* __restrict__ s, const float* __restrict__ hs,
                               float* __restrict__ outacc, int c0, int c1) {
    int w = threadIdx.x >> 6;
    int lane = threadIdx.x & 63;
    int e = blockIdx.x * 4 + w;
    if (e >= NEDGE) return;
    int src = ei[e];
    if (src < c0 || src >= c1) return;
    int dst = ei[NEDGE + e];
    int hh = lane & 7;
    float ev = eb[(size_t)e * 8 + hh];
    float sv = s[(size_t)dst * 8 + hh];
    float wv = ev / (8.f * (sv + 1e-16f));   // alpha/H
    int c = lane << 1;
    float accx = 0.f, accy = 0.f;
    size_t hbase = (size_t)(src - c0) * HCC;
    #pragma unroll
    for (int h = 0; h < 8; ++h) {
        float wh = __shfl(wv, h, 64);
        float2 hv = *(const float2*)&hs[hbase + h * CC + c];
        accx += wh * hv.x;
        accy += wh * hv.y;
    }
    atomicAdd(&outacc[(size_t)dst * CC + c], accx);
    atomicAdd(&outacc[(size_t)dst * CC + c + 1], accy);
}

// ---------------- kernel F: y = elu(LN(o + bias + x@R)) + x ----------------
// NOTE: safe when y aliases x (in-place): each block reads x rows [m0,m0+64)
// into LDS before its only writes, and blocks never touch other blocks' rows.
__global__ __launch_bounds__(256) void finalize_kernel(const float* __restrict__ o, const float* __restrict__ bias,
                                const float* __restrict__ x, const float* __restrict__ R,
                                const float* __restrict__ g, const float* __restrict__ bb,
                                float* __restrict__ y, int M) {
    __shared__ float Xt[128][68];    // x^T tile
    __shared__ float Rs[128][132];   // full R
    int tid = threadIdx.x;
    int m0 = blockIdx.x * 64;
    #pragma unroll
    for (int r = 0; r < 8; ++r) {
        int q = r * 256 + tid;
        int row = q >> 5;
        int k4 = (q & 31) << 2;
        float4 f = make_float4(0.f, 0.f, 0.f, 0.f);
        if (m0 + row < M) f = *(const float4*)&x[(size_t)(m0 + row) * CC + k4];
        Xt[k4][row] = f.x; Xt[k4 + 1][row] = f.y; Xt[k4 + 2][row] = f.z; Xt[k4 + 3][row] = f.w;
    }
    #pragma unroll
    for (int r = 0; r < 16; ++r) {
        int q = r * 256 + tid;           // 4096 float4
        int kr = q >> 5;
        int c4 = (q & 31) << 2;
        *(float4*)&Rs[kr][c4] = *(const float4*)&R[(size_t)kr * CC + c4];
    }
    __syncthreads();
    int tx = tid & 15, ty = tid >> 4;
    int c0 = tx << 3;
    float t[4][8];
    #pragma unroll
    for (int i = 0; i < 4; ++i)
        #pragma unroll
        for (int j = 0; j < 8; ++j) t[i][j] = 0.f;
    #pragma unroll 2
    for (int k = 0; k < 128; ++k) {
        float4 av = *(float4*)&Xt[k][ty << 2];
        float4 r0 = *(float4*)&Rs[k][c0];
        float4 r1 = *(float4*)&Rs[k][c0 + 4];
        float a0 = av.x, a1 = av.y, a2 = av.z, a3 = av.w;
        t[0][0] += a0 * r0.x; t[0][1] += a0 * r0.y; t[0][2] += a0 * r0.z; t[0][3] += a0 * r0.w;
        t[0][4] += a0 * r1.x; t[0][5] += a0 * r1.y; t[0][6] += a0 * r1.z; t[0][7] += a0 * r1.w;
        t[1][0] += a1 * r0.x; t[1][1] += a1 * r0.y; t[1][2] += a1 * r0.z; t[1][3] += a1 * r0.w;
        t[1][4] += a1 * r1.x; t[1][5] += a1 * r1.y; t[1][6] += a1 * r1.z; t[1][7] += a1 * r1.w;
        t[2][0] += a2 * r0.x; t[2][1] += a2 * r0.y; t[2][2] += a2 * r0.z; t[2][3] += a2 * r0.w;
        t[2][4] += a2 * r1.x; t[2][5] += a2 * r1.y; t[2][6] += a2 * r1.z; t[2][7] += a2 * r1.w;
        t[3][0] += a3 * r0.x; t[3][1] += a3 * r0.y; t[3][2] += a3 * r0.z; t[3][3] += a3 * r0.w;
        t[3][4] += a3 * r1.x; t[3][5] += a3 * r1.y; t[3][6] += a3 * r1.z; t[3][7] += a3 * r1.w;
    }
    float4 g0 = *(const float4*)&g[c0];
    float4 g1 = *(const float4*)&g[c0 + 4];
    float4 b0 = *(const float4*)&bb[c0];
    float4 b1 = *(const float4*)&bb[c0 + 4];
    float4 bi0 = *(const float4*)&bias[c0];
    float4 bi1 = *(const float4*)&bias[c0 + 4];
    float gv[8] = { g0.x, g0.y, g0.z, g0.w, g1.x, g1.y, g1.z, g1.w };
    float bv[8] = { b0.x, b0.y, b0.z, b0.w, b1.x, b1.y, b1.z, b1.w };
    float biv[8] = { bi0.x, bi0.y, bi0.z, bi0.w, bi1.x, bi1.y, bi1.z, bi1.w };
    #pragma unroll
    for (int i = 0; i < 4; ++i) {
        int m = m0 + (ty << 2) + i;
        bool valid = (m < M);
        float s1 = 0.f, s2 = 0.f;
        if (valid) {
            float4 o0 = *(const float4*)&o[(size_t)m * CC + c0];
            float4 o1 = *(const float4*)&o[(size_t)m * CC + c0 + 4];
            float ov[8] = { o0.x, o0.y, o0.z, o0.w, o1.x, o1.y, o1.z, o1.w };
            #pragma unroll
            for (int j = 0; j < 8; ++j) {
                float val = t[i][j] + ov[j] + biv[j];
                t[i][j] = val;
                s1 += val;
                s2 += val * val;
            }
        }
        // reduce over the 16 tx lanes (same validity within a ty group)
        #pragma unroll
        for (int off = 1; off < 16; off <<= 1) {
            s1 += __shfl_xor(s1, off, 64);
            s2 += __shfl_xor(s2, off, 64);
        }
        if (valid) {
            float mean = s1 * (1.f / 128.f);
            float var = s2 * (1.f / 128.f) - mean * mean;
            float rstd = rsqrtf(var + 1e-5f);
            float res[8];
            #pragma unroll
            for (int j = 0; j < 8; ++j) {
                float nv = (t[i][j] - mean) * rstd * gv[j] + bv[j];
                float el = (nv > 0.f) ? nv : expm1f(nv);
                res[j] = el + Xt[c0 + j][(ty << 2) + i];
            }
            *(float4*)&y[(size_t)m * CC + c0]     = make_float4(res[0], res[1], res[2], res[3]);
            *(float4*)&y[(size_t)m * CC + c0 + 4] = make_float4(res[4], res[5], res[6], res[7]);
        }
    }
}

extern "C" void kernel_launch(void* const* d_in, const int* in_sizes, int n_in,
                              void* d_out, int out_size, void* d_ws, size_t ws_size,
                              hipStream_t stream) {
    const float* xu_in   = (const float*)d_in[0];
    const float* xi_in   = (const float*)d_in[1];
    const int*   ei_ui   = (const int*)d_in[2];
    const int*   ei_iu   = (const int*)d_in[3];
    const float* Wsrc_ui = (const float*)d_in[4];
    const float* Wdst_ui = (const float*)d_in[5];
    const float* asrc_ui = (const float*)d_in[6];
    const float* adst_ui = (const float*)d_in[7];
    const float* b_ui    = (const float*)d_in[8];
    const float* Wsrc_iu = (const float*)d_in[9];
    const float* Wdst_iu = (const float*)d_in[10];
    const float* asrc_iu = (const float*)d_in[11];
    const float* adst_iu = (const float*)d_in[12];
    const float* b_iu    = (const float*)d_in[13];
    const float* Ru      = (const float*)d_in[14];
    const float* Ri      = (const float*)d_in[15];
    const float* gu      = (const float*)d_in[16];
    const float* bu      = (const float*)d_in[17];
    const float* gi      = (const float*)d_in[18];
    const float* bi      = (const float*)d_in[19];
    float* out = (float*)d_out;          // [y_u (6.4M) | y_i (6.4M)]

    // Layer-0 outputs live directly in d_out; layer-1 finalize runs in-place.
    float* xu1 = out;
    float* xi1 = out + 6400000;

    // ---- workspace layout (hs chunk sized against actual ws_size) ----
    const size_t fixed_floats = 6400000ull * 2 + 400000ull * 6 + 1200000ull + 4096ull; // 16.4M
    size_t avail_floats = ws_size / 4;
    size_t hs_budget = (avail_floats > fixed_floats) ? (avail_floats - fixed_floats) : 0;
    int chunk_rows = (int)(hs_budget / HCC);
    if (chunk_rows > NU) chunk_rows = NU;
    chunk_rows &= ~63;                     // multiple of 64
    if (chunk_rows < 64) chunk_rows = 64;  // last-resort floor
    const int nchunk_sets = (NU + chunk_rows - 1) / chunk_rows;

    float* ws = (float*)d_ws;
    size_t off = 0;
    float* hs     = ws + off; off += (size_t)chunk_rows * HCC;
    float* acc_i  = ws + off; off += 6400000;
    float* acc_u  = ws + off; off += 6400000;
    float* al_s_ui = ws + off; off += 400000;
    float* al_d_ui = ws + off; off += 400000;
    float* al_s_iu = ws + off; off += 400000;
    float* al_d_iu = ws + off; off += 400000;
    float* s_ui   = ws + off; off += 400000;
    float* s_iu   = ws + off; off += 400000;
    float* eb     = ws + off; off += 1200000;
    float* v4     = ws + off; off += 4096;

    const int edge_blocks  = (NEDGE + 255) / 256;
    const int wave_blocks  = (NEDGE + 3) / 4;

    for (int l = 0; l < 2; ++l) {
        const float* xu = (l == 0) ? xu_in : xu1;
        const float* xi = (l == 0) ? xi_in : xi1;
        float* yu = (l == 0) ? xu1 : out;               // layer 1: in-place over xu1
        float* yi = (l == 0) ? xi1 : out + 6400000;     // layer 1: in-place over xi1

        hipMemsetAsync(acc_i, 0, 6400000 * sizeof(float), stream);
        hipMemsetAsync(acc_u, 0, 6400000 * sizeof(float), stream);
        hipMemsetAsync(s_ui, 0, 400000 * sizeof(float), stream);
        hipMemsetAsync(s_iu, 0, 400000 * sizeof(float), stream);

        fold_kernel<<<16, 256, 0, stream>>>(
            Wsrc_ui + (size_t)l * 131072, asrc_ui + (size_t)l * 1024,
            Wdst_ui + (size_t)l * 131072, adst_ui + (size_t)l * 1024,
            Wsrc_iu + (size_t)l * 131072, asrc_iu + (size_t)l * 1024,
            Wdst_iu + (size_t)l * 131072, adst_iu + (size_t)l * 1024, v4);

        al_kernel<<<dim3(1563, 4), 256, 0, stream>>>(xu, xi, v4,
                                                     al_s_ui, al_d_ui, al_s_iu, al_d_iu);

        // ---- edge type ui: src = users, dst = items -> acc_i ----
        edge_exp_kernel<<<edge_blocks, 256, 0, stream>>>(ei_ui, al_s_ui, al_d_ui, eb, s_ui);
        for (int cs = 0; cs < nchunk_sets; ++cs) {
            int c0 = cs * chunk_rows;
            int rows = (NU - c0 < chunk_rows) ? (NU - c0) : chunk_rows;
            gemm_hs_kernel<<<dim3((rows + 63) / 64, 16), 256, 0, stream>>>(
                xu + (size_t)c0 * CC, Wsrc_ui + (size_t)l * 131072, hs, rows);
            scatter_kernel<<<wave_blocks, 256, 0, stream>>>(ei_ui, eb, s_ui, hs, acc_i, c0, c0 + rows);
        }

        // ---- edge type iu: src = items, dst = users -> acc_u ----
        edge_exp_kernel<<<edge_blocks, 256, 0, stream>>>(ei_iu, al_s_iu, al_d_iu, eb, s_iu);
        for (int cs = 0; cs < nchunk_sets; ++cs) {
            int c0 = cs * chunk_rows;
            int rows = (NI - c0 < chunk_rows) ? (NI - c0) : chunk_rows;
            gemm_hs_kernel<<<dim3((rows + 63) / 64, 16), 256, 0, stream>>>(
                xi + (size_t)c0 * CC, Wsrc_iu + (size_t)l * 131072, hs, rows);
            scatter_kernel<<<wave_blocks, 256, 0, stream>>>(ei_iu, eb, s_iu, hs, acc_u, c0, c0 + rows);
        }

        // ---- finalize (layer 1 runs in-place: y aliases x) ----
        finalize_kernel<<<782, 256, 0, stream>>>(acc_i, b_ui + (size_t)l * 128, xi,
                                                 Ri + (size_t)l * 16384, gi + (size_t)l * 128,
                                                 bi + (size_t)l * 128, yi, NI);
        finalize_kernel<<<782, 256, 0, stream>>>(acc_u, b_iu + (size_t)l * 128, xu,
                                                 Ru + (size_t)l * 16384, gu + (size_t)l * 128,
                                                 bu + (size_t)l * 128, yu, NU);
    }
}

// Round 8
// 1892.536 us; speedup vs baseline: 1.2555x; 1.2555x over previous
//
#include <hip/hip_runtime.h>
#include <hip/hip_bf16.h>

#define NU 50000
#define NI 50000
#define NN 50000          // both node sets are 50000
#define NEDGE 150000
#define CC 128
#define HH 8
#define HCC 1024

// ---------------- kernel A: fold attention vectors ----------------
// v[mat][cin][h] = sum_c W[cin, h*128+c] * a[h, c]
__global__ void fold_kernel(const float* __restrict__ W0, const float* __restrict__ a0,
                            const float* __restrict__ W1, const float* __restrict__ a1,
                            const float* __restrict__ W2, const float* __restrict__ a2,
                            const float* __restrict__ W3, const float* __restrict__ a3,
                            float* __restrict__ v4) {
    int gid = blockIdx.x * blockDim.x + threadIdx.x;   // 4096 total
    if (gid >= 4096) return;
    int mat = gid >> 10;
    int rem = gid & 1023;
    int cin = rem >> 3;
    int h   = rem & 7;
    const float* W = (mat == 0) ? W0 : (mat == 1) ? W1 : (mat == 2) ? W2 : W3;
    const float* a = (mat == 0) ? a0 : (mat == 1) ? a1 : (mat == 2) ? a2 : a3;
    const float* wrow = W + (size_t)cin * HCC + h * CC;
    const float* arow = a + h * CC;
    float acc = 0.f;
    #pragma unroll 8
    for (int c = 0; c < CC; ++c) acc += wrow[c] * arow[c];
    v4[gid] = acc;   // layout [mat][cin*8+h]
}

// ---------------- kernel B: attention logits per node ----------------
// cfg 0: al_s_ui = x_u @ v0 ; cfg 1: al_d_ui = x_i @ v1
// cfg 2: al_s_iu = x_i @ v2 ; cfg 3: al_d_iu = x_u @ v3
__global__ __launch_bounds__(256) void al_kernel(const float* __restrict__ xu, const float* __restrict__ xi,
                          const float* __restrict__ v4,
                          float* __restrict__ al0, float* __restrict__ al1,
                          float* __restrict__ al2, float* __restrict__ al3) {
    __shared__ float xs[32][132];
    __shared__ float vs[1024];
    int cfg = blockIdx.y;
    const float* x = (cfg == 0 || cfg == 3) ? xu : xi;
    int n = NN;
    float* out = (cfg == 0) ? al0 : (cfg == 1) ? al1 : (cfg == 2) ? al2 : al3;
    const float* v = v4 + cfg * 1024;
    int n0 = blockIdx.x * 32;
    int tid = threadIdx.x;
    #pragma unroll
    for (int r = 0; r < 4; ++r) vs[tid + r * 256] = v[tid + r * 256];
    #pragma unroll
    for (int r = 0; r < 4; ++r) {
        int q = tid + r * 256;            // float4 id, 1024 total
        int row = q >> 5;
        int c4 = (q & 31) << 2;
        float4 f = make_float4(0.f, 0.f, 0.f, 0.f);
        if (n0 + row < n) f = *(const float4*)&x[(size_t)(n0 + row) * CC + c4];
        xs[row][c4] = f.x; xs[row][c4 + 1] = f.y; xs[row][c4 + 2] = f.z; xs[row][c4 + 3] = f.w;
    }
    __syncthreads();
    int nl = tid >> 3, h = tid & 7;
    if (n0 + nl < n) {
        float acc = 0.f;
        #pragma unroll 8
        for (int c = 0; c < CC; ++c) acc += xs[nl][c] * vs[c * 8 + h];
        out[(size_t)(n0 + nl) * 8 + h] = acc;
    }
}

// ---------------- CSR build: histogram, scan, fill ----------------
__global__ void csr_hist_kernel(const int* __restrict__ ei_ui, const int* __restrict__ ei_iu,
                                int* __restrict__ cnt_ui, int* __restrict__ cnt_iu) {
    int t = blockIdx.x * 256 + threadIdx.x;
    if (t < NEDGE) {
        atomicAdd(&cnt_ui[ei_ui[NEDGE + t]], 1);
    } else if (t < 2 * NEDGE) {
        int e = t - NEDGE;
        atomicAdd(&cnt_iu[ei_iu[NEDGE + e]], 1);
    }
}

// grid=2 (one block per edge type), block=1024; 8 elems/thread per pass
__global__ __launch_bounds__(1024) void csr_scan_kernel(
        const int* __restrict__ cnt_ui, int* __restrict__ off_ui, int* __restrict__ cur_ui,
        const int* __restrict__ cnt_iu, int* __restrict__ off_iu, int* __restrict__ cur_iu) {
    const int* cnt = blockIdx.x ? cnt_iu : cnt_ui;
    int* off = blockIdx.x ? off_iu : off_ui;
    int* cur = blockIdx.x ? cur_iu : cur_ui;
    __shared__ int tmp[1024];
    __shared__ int carry_s;
    int t = threadIdx.x;
    if (t == 0) carry_s = 0;
    __syncthreads();
    for (int base = 0; base < NN; base += 8192) {
        int carry = carry_s;                 // read before any update this iter
        int v[8]; int s = 0;
        int i0 = base + t * 8;
        #pragma unroll
        for (int j = 0; j < 8; ++j) { int idx = i0 + j; v[j] = (idx < NN) ? cnt[idx] : 0; s += v[j]; }
        tmp[t] = s; __syncthreads();
        int incl = s;
        for (int d = 1; d < 1024; d <<= 1) {
            int val = (t >= d) ? tmp[t - d] : 0;
            __syncthreads();
            incl += val;
            tmp[t] = incl;
            __syncthreads();
        }
        int run = carry + incl - s;          // exclusive prefix for first elem
        #pragma unroll
        for (int j = 0; j < 8; ++j) {
            int idx = i0 + j;
            if (idx < NN) { off[idx] = run; cur[idx] = run; }
            run += v[j];
        }
        __syncthreads();
        if (t == 1023) carry_s = carry + incl;   // incl of last thread = block total + carry
        __syncthreads();
    }
    if (t == 0) off[NN] = carry_s;
}

__global__ void csr_fill_kernel(const int* __restrict__ ei_ui, const int* __restrict__ ei_iu,
                                int* __restrict__ cur_ui, int* __restrict__ cur_iu,
                                int* __restrict__ perm_ui, int* __restrict__ perm_iu) {
    int t = blockIdx.x * 256 + threadIdx.x;
    if (t < NEDGE) {
        int dst = ei_ui[NEDGE + t];
        int slot = atomicAdd(&cur_ui[dst], 1);
        perm_ui[slot] = t;
    } else if (t < 2 * NEDGE) {
        int e = t - NEDGE;
        int dst = ei_iu[NEDGE + e];
        int slot = atomicAdd(&cur_iu[dst], 1);
        perm_iu[slot] = e;
    }
}

// ---------------- kernel G: per-dst aggregation in input space ----------------
// agg[d][h][c] = sum_{e: dst(e)=d} [exp(lrelu(al_s[src][h]+al_d[d][h])) / (8*(s_d_h+1e-16))] * x[src][c]
// One wave per dst node. Lane l: head hl = l&7 for weights; channels {2l, 2l+1} for features.
__global__ __launch_bounds__(256) void agg_kernel(const int* __restrict__ ei,
                           const int* __restrict__ off, const int* __restrict__ perm,
                           const float* __restrict__ al_s, const float* __restrict__ al_d,
                           const float* __restrict__ x, float* __restrict__ agg) {
    int wv = (blockIdx.x * 256 + threadIdx.x) >> 6;   // dst node id
    int lane = threadIdx.x & 63;
    if (wv >= NN) return;
    int e0 = off[wv], e1 = off[wv + 1];
    int hl = lane & 7;
    float ald = al_d[(size_t)wv * 8 + hl];
    // pass 1: softmax denominator for head hl (replicated across 8 lane-groups)
    float s = 0.f;
    for (int q = e0; q < e1; ++q) {
        int e = perm[q];
        int src = ei[e];
        float t = al_s[(size_t)src * 8 + hl] + ald;
        t = (t > 0.f) ? t : 0.2f * t;
        s += expf(t);
    }
    float inv = 1.f / (8.f * (s + 1e-16f));
    // pass 2: weighted feature accumulation
    float acc[8][2];
    #pragma unroll
    for (int h = 0; h < 8; ++h) { acc[h][0] = 0.f; acc[h][1] = 0.f; }
    int c = lane << 1;
    for (int q = e0; q < e1; ++q) {
        int e = perm[q];
        int src = ei[e];
        float t = al_s[(size_t)src * 8 + hl] + ald;
        t = (t > 0.f) ? t : 0.2f * t;
        float w = expf(t) * inv;                     // alpha/8 for head hl
        float2 xv = *(const float2*)&x[(size_t)src * CC + c];
        #pragma unroll
        for (int h = 0; h < 8; ++h) {
            float wh = __shfl(w, h, 64);             // lane h holds head h's weight
            acc[h][0] += wh * xv.x;
            acc[h][1] += wh * xv.y;
        }
    }
    #pragma unroll
    for (int h = 0; h < 8; ++h) {
        *(float2*)&agg[(size_t)wv * HCC + h * CC + c] = make_float2(acc[h][0], acc[h][1]);
    }
}

// ---------------- kernel H: block-diagonal projection ----------------
// out[n][j] = sum_h sum_c agg[n][h*128+c] * W[c][h*128+j]   (1/8 already folded into agg)
// tile: 64 m x 64 j, K-loop over 8 heads x 128 c. Writes out directly (no atomics).
__global__ __launch_bounds__(256) void proj_kernel(const float* __restrict__ agg, const float* __restrict__ W,
                            float* __restrict__ outp) {
    __shared__ float As[64][132];   // row-major [m][c-within-head]
    __shared__ float Bs[128][68];   // [c][j-within-tile]
    int tid = threadIdx.x;
    int m0 = blockIdx.x * 64;
    int j0 = blockIdx.y * 64;
    int tx = tid & 15, ty = tid >> 4;
    float acc[4][4];
    #pragma unroll
    for (int i = 0; i < 4; ++i)
        #pragma unroll
        for (int j = 0; j < 4; ++j) acc[i][j] = 0.f;

    for (int h = 0; h < 8; ++h) {
        __syncthreads();   // protect LDS from previous head's readers
        #pragma unroll
        for (int r = 0; r < 8; ++r) {
            int q = r * 256 + tid;            // 2048 float4: A tile rows
            int m = q >> 5;
            int k4 = (q & 31) << 2;
            float4 f = make_float4(0.f, 0.f, 0.f, 0.f);
            if (m0 + m < NN) f = *(const float4*)&agg[(size_t)(m0 + m) * HCC + h * CC + k4];
            *(float4*)&As[m][k4] = f;
        }
        #pragma unroll
        for (int r = 0; r < 8; ++r) {
            int q = r * 256 + tid;            // 2048 float4: B tile
            int k = q >> 4;
            int j4 = (q & 15) << 2;
            *(float4*)&Bs[k][j4] = *(const float4*)&W[(size_t)k * HCC + h * CC + j0 + j4];
        }
        __syncthreads();
        #pragma unroll 4
        for (int k4 = 0; k4 < 32; ++k4) {
            int kb = k4 << 2;
            float4 a0 = *(float4*)&As[(ty << 2) + 0][kb];
            float4 a1 = *(float4*)&As[(ty << 2) + 1][kb];
            float4 a2 = *(float4*)&As[(ty << 2) + 2][kb];
            float4 a3 = *(float4*)&As[(ty << 2) + 3][kb];
            float4 b0 = *(float4*)&Bs[kb + 0][tx << 2];
            float4 b1 = *(float4*)&Bs[kb + 1][tx << 2];
            float4 b2 = *(float4*)&Bs[kb + 2][tx << 2];
            float4 b3 = *(float4*)&Bs[kb + 3][tx << 2];
            acc[0][0] += a0.x*b0.x + a0.y*b1.x + a0.z*b2.x + a0.w*b3.x;
            acc[0][1] += a0.x*b0.y + a0.y*b1.y + a0.z*b2.y + a0.w*b3.y;
            acc[0][2] += a0.x*b0.z + a0.y*b1.z + a0.z*b2.z + a0.w*b3.z;
            acc[0][3] += a0.x*b0.w + a0.y*b1.w + a0.z*b2.w + a0.w*b3.w;
            acc[1][0] += a1.x*b0.x + a1.y*b1.x + a1.z*b2.x + a1.w*b3.x;
            acc[1][1] += a1.x*b0.y + a1.y*b1.y + a1.z*b2.y + a1.w*b3.y;
            acc[1][2] += a1.x*b0.z + a1.y*b1.z + a1.z*b2.z + a1.w*b3.z;
            acc[1][3] += a1.x*b0.w + a1.y*b1.w + a1.z*b2.w + a1.w*b3.w;
            acc[2][0] += a2.x*b0.x + a2.y*b1.x + a2.z*b2.x + a2.w*b3.x;
            acc[2][1] += a2.x*b0.y + a2.y*b1.y + a2.z*b2.y + a2.w*b3.y;
            acc[2][2] += a2.x*b0.z + a2.y*b1.z + a2.z*b2.z + a2.w*b3.z;
            acc[2][3] += a2.x*b0.w + a2.y*b1.w + a2.z*b2.w + a2.w*b3.w;
            acc[3][0] += a3.x*b0.x + a3.y*b1.x + a3.z*b2.x + a3.w*b3.x;
            acc[3][1] += a3.x*b0.y + a3.y*b1.y + a3.z*b2.y + a3.w*b3.y;
            acc[3][2] += a3.x*b0.z + a3.y*b1.z + a3.z*b2.z + a3.w*b3.z;
            acc[3][3] += a3.x*b0.w + a3.y*b1.w + a3.z*b2.w + a3.w*b3.w;
        }
    }
    #pragma unroll
    for (int i = 0; i < 4; ++i) {
        int m = m0 + (ty << 2) + i;
        if (m < NN) {
            float4 o = make_float4(acc[i][0], acc[i][1], acc[i][2], acc[i][3]);
            *(float4*)&outp[(size_t)m * CC + j0 + (tx << 2)] = o;
        }
    }
}

// ---------------- kernel F: y = elu(LN(o + bias + x@R)) + x ----------------
// Safe when y aliases x (in-place): block reads its x rows into LDS first.
__global__ __launch_bounds__(256) void finalize_kernel(const float* __restrict__ o, const float* __restrict__ bias,
                                const float* __restrict__ x, const float* __restrict__ R,
                                const float* __restrict__ g, const float* __restrict__ bb,
                                float* __restrict__ y, int M) {
    __shared__ float Xt[128][68];    // x^T tile
    __shared__ float Rs[128][132];   // full R
    int tid = threadIdx.x;
    int m0 = blockIdx.x * 64;
    #pragma unroll
    for (int r = 0; r < 8; ++r) {
        int q = r * 256 + tid;
        int row = q >> 5;
        int k4 = (q & 31) << 2;
        float4 f = make_float4(0.f, 0.f, 0.f, 0.f);
        if (m0 + row < M) f = *(const float4*)&x[(size_t)(m0 + row) * CC + k4];
        Xt[k4][row] = f.x; Xt[k4 + 1][row] = f.y; Xt[k4 + 2][row] = f.z; Xt[k4 + 3][row] = f.w;
    }
    #pragma unroll
    for (int r = 0; r < 16; ++r) {
        int q = r * 256 + tid;           // 4096 float4
        int kr = q >> 5;
        int c4 = (q & 31) << 2;
        *(float4*)&Rs[kr][c4] = *(const float4*)&R[(size_t)kr * CC + c4];
    }
    __syncthreads();
    int tx = tid & 15, ty = tid >> 4;
    int c0 = tx << 3;
    float t[4][8];
    #pragma unroll
    for (int i = 0; i < 4; ++i)
        #pragma unroll
        for (int j = 0; j < 8; ++j) t[i][j] = 0.f;
    #pragma unroll 2
    for (int k = 0; k < 128; ++k) {
        float4 av = *(float4*)&Xt[k][ty << 2];
        float4 r0 = *(float4*)&Rs[k][c0];
        float4 r1 = *(float4*)&Rs[k][c0 + 4];
        float a0 = av.x, a1 = av.y, a2 = av.z, a3 = av.w;
        t[0][0] += a0 * r0.x; t[0][1] += a0 * r0.y; t[0][2] += a0 * r0.z; t[0][3] += a0 * r0.w;
        t[0][4] += a0 * r1.x; t[0][5] += a0 * r1.y; t[0][6] += a0 * r1.z; t[0][7] += a0 * r1.w;
        t[1][0] += a1 * r0.x; t[1][1] += a1 * r0.y; t[1][2] += a1 * r0.z; t[1][3] += a1 * r0.w;
        t[1][4] += a1 * r1.x; t[1][5] += a1 * r1.y; t[1][6] += a1 * r1.z; t[1][7] += a1 * r1.w;
        t[2][0] += a2 * r0.x; t[2][1] += a2 * r0.y; t[2][2] += a2 * r0.z; t[2][3] += a2 * r0.w;
        t[2][4] += a2 * r1.x; t[2][5] += a2 * r1.y; t[2][6] += a2 * r1.z; t[2][7] += a2 * r1.w;
        t[3][0] += a3 * r0.x; t[3][1] += a3 * r0.y; t[3][2] += a3 * r0.z; t[3][3] += a3 * r0.w;
        t[3][4] += a3 * r1.x; t[3][5] += a3 * r1.y; t[3][6] += a3 * r1.z; t[3][7] += a3 * r1.w;
    }
    float4 g0 = *(const float4*)&g[c0];
    float4 g1 = *(const float4*)&g[c0 + 4];
    float4 b0 = *(const float4*)&bb[c0];
    float4 b1 = *(const float4*)&bb[c0 + 4];
    float4 bi0 = *(const float4*)&bias[c0];
    float4 bi1 = *(const float4*)&bias[c0 + 4];
    float gv[8] = { g0.x, g0.y, g0.z, g0.w, g1.x, g1.y, g1.z, g1.w };
    float bv[8] = { b0.x, b0.y, b0.z, b0.w, b1.x, b1.y, b1.z, b1.w };
    float biv[8] = { bi0.x, bi0.y, bi0.z, bi0.w, bi1.x, bi1.y, bi1.z, bi1.w };
    #pragma unroll
    for (int i = 0; i < 4; ++i) {
        int m = m0 + (ty << 2) + i;
        bool valid = (m < M);
        float s1 = 0.f, s2 = 0.f;
        if (valid) {
            float4 o0 = *(const float4*)&o[(size_t)m * CC + c0];
            float4 o1 = *(const float4*)&o[(size_t)m * CC + c0 + 4];
            float ov[8] = { o0.x, o0.y, o0.z, o0.w, o1.x, o1.y, o1.z, o1.w };
            #pragma unroll
            for (int j = 0; j < 8; ++j) {
                float val = t[i][j] + ov[j] + biv[j];
                t[i][j] = val;
                s1 += val;
                s2 += val * val;
            }
        }
        #pragma unroll
        for (int off = 1; off < 16; off <<= 1) {
            s1 += __shfl_xor(s1, off, 64);
            s2 += __shfl_xor(s2, off, 64);
        }
        if (valid) {
            float mean = s1 * (1.f / 128.f);
            float var = s2 * (1.f / 128.f) - mean * mean;
            float rstd = rsqrtf(var + 1e-5f);
            float res[8];
            #pragma unroll
            for (int j = 0; j < 8; ++j) {
                float nv = (t[i][j] - mean) * rstd * gv[j] + bv[j];
                float el = (nv > 0.f) ? nv : expm1f(nv);
                res[j] = el + Xt[c0 + j][(ty << 2) + i];
            }
            *(float4*)&y[(size_t)m * CC + c0]     = make_float4(res[0], res[1], res[2], res[3]);
            *(float4*)&y[(size_t)m * CC + c0 + 4] = make_float4(res[4], res[5], res[6], res[7]);
        }
    }
}

extern "C" void kernel_launch(void* const* d_in, const int* in_sizes, int n_in,
                              void* d_out, int out_size, void* d_ws, size_t ws_size,
                              hipStream_t stream) {
    const float* xu_in   = (const float*)d_in[0];
    const float* xi_in   = (const float*)d_in[1];
    const int*   ei_ui   = (const int*)d_in[2];
    const int*   ei_iu   = (const int*)d_in[3];
    const float* Wsrc_ui = (const float*)d_in[4];
    const float* Wdst_ui = (const float*)d_in[5];
    const float* asrc_ui = (const float*)d_in[6];
    const float* adst_ui = (const float*)d_in[7];
    const float* b_ui    = (const float*)d_in[8];
    const float* Wsrc_iu = (const float*)d_in[9];
    const float* Wdst_iu = (const float*)d_in[10];
    const float* asrc_iu = (const float*)d_in[11];
    const float* adst_iu = (const float*)d_in[12];
    const float* b_iu    = (const float*)d_in[13];
    const float* Ru      = (const float*)d_in[14];
    const float* Ri      = (const float*)d_in[15];
    const float* gu      = (const float*)d_in[16];
    const float* bu      = (const float*)d_in[17];
    const float* gi      = (const float*)d_in[18];
    const float* bi      = (const float*)d_in[19];
    float* out = (float*)d_out;          // [y_u (6.4M) | y_i (6.4M)]

    // Layer-0 outputs live directly in d_out; layer-1 finalize runs in-place.
    float* xu1 = out;
    float* xi1 = out + 6400000;

    // ---- workspace layout (~265 MB; ws_size >= 270.4 MB proven by R3 run) ----
    float* ws = (float*)d_ws;
    size_t off = 0;
    float* agg    = ws + off; off += (size_t)NN * HCC;      // 51.2M
    float* acc_i  = ws + off; off += 6400000;
    float* acc_u  = ws + off; off += 6400000;
    float* al_s_ui = ws + off; off += 400000;
    float* al_d_ui = ws + off; off += 400000;
    float* al_s_iu = ws + off; off += 400000;
    float* al_d_iu = ws + off; off += 400000;
    float* v4     = ws + off; off += 4096;
    int* ib = (int*)(ws + off);
    size_t ioff = 0;
    int* off_ui  = ib + ioff; ioff += NN + 1;
    int* off_iu  = ib + ioff; ioff += NN + 1;
    int* cur_ui  = ib + ioff; ioff += NN;
    int* cur_iu  = ib + ioff; ioff += NN;
    int* cnt_ui  = ib + ioff; ioff += NN;
    int* cnt_iu  = ib + ioff; ioff += NN;
    int* perm_ui = ib + ioff; ioff += NEDGE;
    int* perm_iu = ib + ioff; ioff += NEDGE;

    // ---- CSR build (edge lists are layer-invariant: build once per call) ----
    hipMemsetAsync(cnt_ui, 0, NN * sizeof(int), stream);
    hipMemsetAsync(cnt_iu, 0, NN * sizeof(int), stream);
    const int ef_blocks = (2 * NEDGE + 255) / 256;
    csr_hist_kernel<<<ef_blocks, 256, 0, stream>>>(ei_ui, ei_iu, cnt_ui, cnt_iu);
    csr_scan_kernel<<<2, 1024, 0, stream>>>(cnt_ui, off_ui, cur_ui, cnt_iu, off_iu, cur_iu);
    csr_fill_kernel<<<ef_blocks, 256, 0, stream>>>(ei_ui, ei_iu, cur_ui, cur_iu, perm_ui, perm_iu);

    const int agg_blocks = (NN * 64 + 255) / 256;   // one wave per dst

    for (int l = 0; l < 2; ++l) {
        const float* xu = (l == 0) ? xu_in : xu1;
        const float* xi = (l == 0) ? xi_in : xi1;
        float* yu = (l == 0) ? xu1 : out;               // layer 1: in-place
        float* yi = (l == 0) ? xi1 : out + 6400000;

        fold_kernel<<<16, 256, 0, stream>>>(
            Wsrc_ui + (size_t)l * 131072, asrc_ui + (size_t)l * 1024,
            Wdst_ui + (size_t)l * 131072, adst_ui + (size_t)l * 1024,
            Wsrc_iu + (size_t)l * 131072, asrc_iu + (size_t)l * 1024,
            Wdst_iu + (size_t)l * 131072, adst_iu + (size_t)l * 1024, v4);

        al_kernel<<<dim3(1563, 4), 256, 0, stream>>>(xu, xi, v4,
                                                     al_s_ui, al_d_ui, al_s_iu, al_d_iu);

        // ---- ui: src=users, dst=items -> acc_i (agg buffer reused sequentially) ----
        agg_kernel<<<agg_blocks, 256, 0, stream>>>(ei_ui, off_ui, perm_ui,
                                                   al_s_ui, al_d_ui, xu, agg);
        proj_kernel<<<dim3(782, 2), 256, 0, stream>>>(agg, Wsrc_ui + (size_t)l * 131072, acc_i);

        // ---- iu: src=items, dst=users -> acc_u ----
        agg_kernel<<<agg_blocks, 256, 0, stream>>>(ei_iu, off_iu, perm_iu,
                                                   al_s_iu, al_d_iu, xi, agg);
        proj_kernel<<<dim3(782, 2), 256, 0, stream>>>(agg, Wsrc_iu + (size_t)l * 131072, acc_u);

        // ---- finalize ----
        finalize_kernel<<<782, 256, 0, stream>>>(acc_i, b_ui + (size_t)l * 128, xi,
                                                 Ri + (size_t)l * 16384, gi + (size_t)l * 128,
                                                 bi + (size_t)l * 128, yi, NI);
        finalize_kernel<<<782, 256, 0, stream>>>(acc_u, b_iu + (size_t)l * 128, xu,
                                                 Ru + (size_t)l * 16384, gu + (size_t)l * 128,
                                                 bu + (size_t)l * 128, yu, NU);
    }
}

// Round 9
// 1744.638 us; speedup vs baseline: 1.3620x; 1.0848x over previous
//
#include <hip/hip_runtime.h>
#include <hip/hip_bf16.h>

#define NU 50000
#define NI 50000
#define NN 50000          // both node sets are 50000
#define NEDGE 150000
#define CC 128
#define HH 8
#define HCC 1024
#define NGRP 3128         // ceil(50048/16) row-groups in tiled A layout

typedef __attribute__((ext_vector_type(8))) short bf16x8;
typedef __attribute__((ext_vector_type(4))) float f32x4;

static __device__ inline ushort bf16_rn(float f) {
    uint u = __float_as_uint(f);
    uint r = (u + 0x7FFFu + ((u >> 16) & 1u)) >> 16;
    return (ushort)r;
}

// ---------------- kernel A: fold attention vectors ----------------
// v[mat][cin][h] = sum_c W[cin, h*128+c] * a[h, c]
__global__ void fold_kernel(const float* __restrict__ W0, const float* __restrict__ a0,
                            const float* __restrict__ W1, const float* __restrict__ a1,
                            const float* __restrict__ W2, const float* __restrict__ a2,
                            const float* __restrict__ W3, const float* __restrict__ a3,
                            float* __restrict__ v4) {
    int gid = blockIdx.x * blockDim.x + threadIdx.x;   // 4096 total
    if (gid >= 4096) return;
    int mat = gid >> 10;
    int rem = gid & 1023;
    int cin = rem >> 3;
    int h   = rem & 7;
    const float* W = (mat == 0) ? W0 : (mat == 1) ? W1 : (mat == 2) ? W2 : W3;
    const float* a = (mat == 0) ? a0 : (mat == 1) ? a1 : (mat == 2) ? a2 : a3;
    const float* wrow = W + (size_t)cin * HCC + h * CC;
    const float* arow = a + h * CC;
    float acc = 0.f;
    #pragma unroll 8
    for (int c = 0; c < CC; ++c) acc += wrow[c] * arow[c];
    v4[gid] = acc;   // layout [mat][cin*8+h]
}

// ---------------- kernel B: attention logits per node ----------------
__global__ __launch_bounds__(256) void al_kernel(const float* __restrict__ xu, const float* __restrict__ xi,
                          const float* __restrict__ v4,
                          float* __restrict__ al0, float* __restrict__ al1,
                          float* __restrict__ al2, float* __restrict__ al3) {
    __shared__ float xs[32][132];
    __shared__ float vs[1024];
    int cfg = blockIdx.y;
    const float* x = (cfg == 0 || cfg == 3) ? xu : xi;
    int n = NN;
    float* out = (cfg == 0) ? al0 : (cfg == 1) ? al1 : (cfg == 2) ? al2 : al3;
    const float* v = v4 + cfg * 1024;
    int n0 = blockIdx.x * 32;
    int tid = threadIdx.x;
    #pragma unroll
    for (int r = 0; r < 4; ++r) vs[tid + r * 256] = v[tid + r * 256];
    #pragma unroll
    for (int r = 0; r < 4; ++r) {
        int q = tid + r * 256;
        int row = q >> 5;
        int c4 = (q & 31) << 2;
        float4 f = make_float4(0.f, 0.f, 0.f, 0.f);
        if (n0 + row < n) f = *(const float4*)&x[(size_t)(n0 + row) * CC + c4];
        xs[row][c4] = f.x; xs[row][c4 + 1] = f.y; xs[row][c4 + 2] = f.z; xs[row][c4 + 3] = f.w;
    }
    __syncthreads();
    int nl = tid >> 3, h = tid & 7;
    if (n0 + nl < n) {
        float acc = 0.f;
        #pragma unroll 8
        for (int c = 0; c < CC; ++c) acc += xs[nl][c] * vs[c * 8 + h];
        out[(size_t)(n0 + nl) * 8 + h] = acc;
    }
}

// ---------------- CSR build: histogram, scan, fill ----------------
__global__ void csr_hist_kernel(const int* __restrict__ ei_ui, const int* __restrict__ ei_iu,
                                int* __restrict__ cnt_ui, int* __restrict__ cnt_iu) {
    int t = blockIdx.x * 256 + threadIdx.x;
    if (t < NEDGE) {
        atomicAdd(&cnt_ui[ei_ui[NEDGE + t]], 1);
    } else if (t < 2 * NEDGE) {
        int e = t - NEDGE;
        atomicAdd(&cnt_iu[ei_iu[NEDGE + e]], 1);
    }
}

__global__ __launch_bounds__(1024) void csr_scan_kernel(
        const int* __restrict__ cnt_ui, int* __restrict__ off_ui, int* __restrict__ cur_ui,
        const int* __restrict__ cnt_iu, int* __restrict__ off_iu, int* __restrict__ cur_iu) {
    const int* cnt = blockIdx.x ? cnt_iu : cnt_ui;
    int* off = blockIdx.x ? off_iu : off_ui;
    int* cur = blockIdx.x ? cur_iu : cur_ui;
    __shared__ int tmp[1024];
    __shared__ int carry_s;
    int t = threadIdx.x;
    if (t == 0) carry_s = 0;
    __syncthreads();
    for (int base = 0; base < NN; base += 8192) {
        int carry = carry_s;
        int v[8]; int s = 0;
        int i0 = base + t * 8;
        #pragma unroll
        for (int j = 0; j < 8; ++j) { int idx = i0 + j; v[j] = (idx < NN) ? cnt[idx] : 0; s += v[j]; }
        tmp[t] = s; __syncthreads();
        int incl = s;
        for (int d = 1; d < 1024; d <<= 1) {
            int val = (t >= d) ? tmp[t - d] : 0;
            __syncthreads();
            incl += val;
            tmp[t] = incl;
            __syncthreads();
        }
        int run = carry + incl - s;
        #pragma unroll
        for (int j = 0; j < 8; ++j) {
            int idx = i0 + j;
            if (idx < NN) { off[idx] = run; cur[idx] = run; }
            run += v[j];
        }
        __syncthreads();
        if (t == 1023) carry_s = carry + incl;
        __syncthreads();
    }
    if (t == 0) off[NN] = carry_s;
}

__global__ void csr_fill_kernel(const int* __restrict__ ei_ui, const int* __restrict__ ei_iu,
                                int* __restrict__ cur_ui, int* __restrict__ cur_iu,
                                int* __restrict__ perm_ui, int* __restrict__ perm_iu) {
    int t = blockIdx.x * 256 + threadIdx.x;
    if (t < NEDGE) {
        int dst = ei_ui[NEDGE + t];
        int slot = atomicAdd(&cur_ui[dst], 1);
        perm_ui[slot] = t;
    } else if (t < 2 * NEDGE) {
        int e = t - NEDGE;
        int dst = ei_iu[NEDGE + e];
        int slot = atomicAdd(&cur_iu[dst], 1);
        perm_iu[slot] = e;
    }
}

// ---------------- kernel P: W -> WstackT bf16 hi/lo ----------------
// WT[j][k] = W[c][h*128+j], k = h*128+c. Output [128][1024] row-major per plane.
__global__ void wprep_kernel(const float* __restrict__ Wui, const float* __restrict__ Wiu,
                             ushort* __restrict__ hi_ui, ushort* __restrict__ lo_ui,
                             ushort* __restrict__ hi_iu, ushort* __restrict__ lo_iu) {
    int idx = blockIdx.x * 256 + threadIdx.x;   // 0..131071
    if (idx >= 131072) return;
    const float* W = blockIdx.y ? Wiu : Wui;
    ushort* ph = blockIdx.y ? hi_iu : hi_ui;
    ushort* pl = blockIdx.y ? lo_iu : lo_ui;
    int j = idx >> 10, k = idx & 1023;
    int h = k >> 7, c = k & 127;
    float v = W[(size_t)c * 1024 + h * 128 + j];
    ushort hh = bf16_rn(v);
    float lo = v - __uint_as_float((uint)hh << 16);
    ph[idx] = hh;
    pl[idx] = bf16_rn(lo);
}

// ---------------- kernel G: per-dst aggregation, writes bf16 hi/lo planes ----------------
// in MFMA A-frag tiled layout: idx(m,k) = ((m>>4)*128 + (k>>3))*128 + (m&15)*8 + (k&7)
__global__ __launch_bounds__(256) void agg_kernel(const int* __restrict__ ei,
                           const int* __restrict__ off, const int* __restrict__ perm,
                           const float* __restrict__ al_s, const float* __restrict__ al_d,
                           const float* __restrict__ x,
                           ushort* __restrict__ aggT_hi, ushort* __restrict__ aggT_lo) {
    int wv = (blockIdx.x * 256 + threadIdx.x) >> 6;   // dst node id
    int lane = threadIdx.x & 63;
    if (wv >= NN) return;
    int e0 = off[wv], e1 = off[wv + 1];
    int hl = lane & 7;
    float ald = al_d[(size_t)wv * 8 + hl];
    float s = 0.f;
    for (int q = e0; q < e1; ++q) {
        int e = perm[q];
        int src = ei[e];
        float t = al_s[(size_t)src * 8 + hl] + ald;
        t = (t > 0.f) ? t : 0.2f * t;
        s += expf(t);
    }
    float inv = 1.f / (8.f * (s + 1e-16f));
    float acc[8][2];
    #pragma unroll
    for (int h = 0; h < 8; ++h) { acc[h][0] = 0.f; acc[h][1] = 0.f; }
    int c = lane << 1;
    for (int q = e0; q < e1; ++q) {
        int e = perm[q];
        int src = ei[e];
        float t = al_s[(size_t)src * 8 + hl] + ald;
        t = (t > 0.f) ? t : 0.2f * t;
        float w = expf(t) * inv;
        float2 xv = *(const float2*)&x[(size_t)src * CC + c];
        #pragma unroll
        for (int h = 0; h < 8; ++h) {
            float wh = __shfl(w, h, 64);
            acc[h][0] += wh * xv.x;
            acc[h][1] += wh * xv.y;
        }
    }
    // split to bf16 hi/lo, store in tiled layout (4B per plane per head)
    int rgrp = wv >> 4, rr = wv & 15;
    #pragma unroll
    for (int h = 0; h < 8; ++h) {
        float v0 = acc[h][0], v1 = acc[h][1];
        ushort h0 = bf16_rn(v0);
        ushort h1 = bf16_rn(v1);
        float l0f = v0 - __uint_as_float((uint)h0 << 16);
        float l1f = v1 - __uint_as_float((uint)h1 << 16);
        ushort l0 = bf16_rn(l0f);
        ushort l1 = bf16_rn(l1f);
        size_t base = ((size_t)rgrp * 128 + h * 16 + (lane >> 2)) * 128 + rr * 8 + ((2 * lane) & 7);
        *(uint*)&aggT_hi[base] = (uint)h0 | ((uint)h1 << 16);
        *(uint*)&aggT_lo[base] = (uint)l0 | ((uint)l1 << 16);
    }
}

// ---------------- kernel H: projection via MFMA, split-bf16 (3-product) ----------------
// C[m][j] = sum_k A[m][k]*B[k][j]; A from tiled global frags, B staged in LDS.
// block: 256 thr = 4 waves; M-tile 64 (16 rows/wave), N = 128 full, BK = 64.
__global__ __launch_bounds__(256) void proj_mfma_kernel(
        const ushort* __restrict__ aggT_hi, const ushort* __restrict__ aggT_lo,
        const ushort* __restrict__ WT_hi, const ushort* __restrict__ WT_lo,
        float* __restrict__ outp) {
    __shared__ __align__(16) ushort Bh[128][72];   // [j][k-in-tile], pad 72 (144B rows)
    __shared__ __align__(16) ushort Bl[128][72];
    int tid = threadIdx.x;
    int w = tid >> 6, lane = tid & 63;
    int m0 = blockIdx.x * 64;
    int a = (m0 >> 4) + w;             // row-group of this wave
    int r = lane & 15, g = lane >> 4;  // frag row / k-group
    f32x4 acc[8];
    #pragma unroll
    for (int nt = 0; nt < 8; ++nt) acc[nt] = (f32x4){0.f, 0.f, 0.f, 0.f};

    for (int kt = 0; kt < 16; ++kt) {
        __syncthreads();   // previous iteration's readers done
        // stage B tile [128][64] hi+lo: 1024 16B chunks per plane, 4/thread
        #pragma unroll
        for (int qq = 0; qq < 4; ++qq) {
            int q = qq * 256 + tid;
            int j = q >> 3, ck = (q & 7) * 8;
            size_t gsrc = (size_t)j * 1024 + kt * 64 + ck;
            *(uint4*)&Bh[j][ck] = *(const uint4*)&WT_hi[gsrc];
            *(uint4*)&Bl[j][ck] = *(const uint4*)&WT_lo[gsrc];
        }
        __syncthreads();
        #pragma unroll
        for (int kk2 = 0; kk2 < 2; ++kk2) {
            int ks = kt * 2 + kk2;         // global 32-wide k-step
            int kb = ks * 4 + g;           // 8-wide k-block
            size_t abase = ((size_t)a * 128 + kb) * 128 + r * 8;
            bf16x8 a_h = *(const bf16x8*)&aggT_hi[abase];
            bf16x8 a_l = *(const bf16x8*)&aggT_lo[abase];
            int ko = kk2 * 32 + g * 8;
            #pragma unroll
            for (int nt = 0; nt < 8; ++nt) {
                bf16x8 b_h = *(const bf16x8*)&Bh[nt * 16 + r][ko];
                bf16x8 b_l = *(const bf16x8*)&Bl[nt * 16 + r][ko];
                acc[nt] = __builtin_amdgcn_mfma_f32_16x16x32_bf16(a_h, b_h, acc[nt], 0, 0, 0);
                acc[nt] = __builtin_amdgcn_mfma_f32_16x16x32_bf16(a_h, b_l, acc[nt], 0, 0, 0);
                acc[nt] = __builtin_amdgcn_mfma_f32_16x16x32_bf16(a_l, b_h, acc[nt], 0, 0, 0);
            }
        }
    }
    // epilogue: D col = lane&15, row = (lane>>4)*4 + reg  [m89-verified mapping]
    #pragma unroll
    for (int nt = 0; nt < 8; ++nt) {
        #pragma unroll
        for (int j = 0; j < 4; ++j) {
            int m = m0 + w * 16 + g * 4 + j;
            if (m < NN) outp[(size_t)m * CC + nt * 16 + r] = acc[nt][j];
        }
    }
}

// ---------------- kernel F: y = elu(LN(o + bias + x@R)) + x ----------------
__global__ __launch_bounds__(256) void finalize_kernel(const float* __restrict__ o, const float* __restrict__ bias,
                                const float* __restrict__ x, const float* __restrict__ R,
                                const float* __restrict__ g, const float* __restrict__ bb,
                                float* __restrict__ y, int M) {
    __shared__ float Xt[128][68];
    __shared__ float Rs[128][132];
    int tid = threadIdx.x;
    int m0 = blockIdx.x * 64;
    #pragma unroll
    for (int r = 0; r < 8; ++r) {
        int q = r * 256 + tid;
        int row = q >> 5;
        int k4 = (q & 31) << 2;
        float4 f = make_float4(0.f, 0.f, 0.f, 0.f);
        if (m0 + row < M) f = *(const float4*)&x[(size_t)(m0 + row) * CC + k4];
        Xt[k4][row] = f.x; Xt[k4 + 1][row] = f.y; Xt[k4 + 2][row] = f.z; Xt[k4 + 3][row] = f.w;
    }
    #pragma unroll
    for (int r = 0; r < 16; ++r) {
        int q = r * 256 + tid;
        int kr = q >> 5;
        int c4 = (q & 31) << 2;
        *(float4*)&Rs[kr][c4] = *(const float4*)&R[(size_t)kr * CC + c4];
    }
    __syncthreads();
    int tx = tid & 15, ty = tid >> 4;
    int c0 = tx << 3;
    float t[4][8];
    #pragma unroll
    for (int i = 0; i < 4; ++i)
        #pragma unroll
        for (int j = 0; j < 8; ++j) t[i][j] = 0.f;
    #pragma unroll 2
    for (int k = 0; k < 128; ++k) {
        float4 av = *(float4*)&Xt[k][ty << 2];
        float4 r0 = *(float4*)&Rs[k][c0];
        float4 r1 = *(float4*)&Rs[k][c0 + 4];
        float a0 = av.x, a1 = av.y, a2 = av.z, a3 = av.w;
        t[0][0] += a0 * r0.x; t[0][1] += a0 * r0.y; t[0][2] += a0 * r0.z; t[0][3] += a0 * r0.w;
        t[0][4] += a0 * r1.x; t[0][5] += a0 * r1.y; t[0][6] += a0 * r1.z; t[0][7] += a0 * r1.w;
        t[1][0] += a1 * r0.x; t[1][1] += a1 * r0.y; t[1][2] += a1 * r0.z; t[1][3] += a1 * r0.w;
        t[1][4] += a1 * r1.x; t[1][5] += a1 * r1.y; t[1][6] += a1 * r1.z; t[1][7] += a1 * r1.w;
        t[2][0] += a2 * r0.x; t[2][1] += a2 * r0.y; t[2][2] += a2 * r0.z; t[2][3] += a2 * r0.w;
        t[2][4] += a2 * r1.x; t[2][5] += a2 * r1.y; t[2][6] += a2 * r1.z; t[2][7] += a2 * r1.w;
        t[3][0] += a3 * r0.x; t[3][1] += a3 * r0.y; t[3][2] += a3 * r0.z; t[3][3] += a3 * r0.w;
        t[3][4] += a3 * r1.x; t[3][5] += a3 * r1.y; t[3][6] += a3 * r1.z; t[3][7] += a3 * r1.w;
    }
    float4 g0 = *(const float4*)&g[c0];
    float4 g1 = *(const float4*)&g[c0 + 4];
    float4 b0 = *(const float4*)&bb[c0];
    float4 b1 = *(const float4*)&bb[c0 + 4];
    float4 bi0 = *(const float4*)&bias[c0];
    float4 bi1 = *(const float4*)&bias[c0 + 4];
    float gv[8] = { g0.x, g0.y, g0.z, g0.w, g1.x, g1.y, g1.z, g1.w };
    float bv[8] = { b0.x, b0.y, b0.z, b0.w, b1.x, b1.y, b1.z, b1.w };
    float biv[8] = { bi0.x, bi0.y, bi0.z, bi0.w, bi1.x, bi1.y, bi1.z, bi1.w };
    #pragma unroll
    for (int i = 0; i < 4; ++i) {
        int m = m0 + (ty << 2) + i;
        bool valid = (m < M);
        float s1 = 0.f, s2 = 0.f;
        if (valid) {
            float4 o0 = *(const float4*)&o[(size_t)m * CC + c0];
            float4 o1 = *(const float4*)&o[(size_t)m * CC + c0 + 4];
            float ov[8] = { o0.x, o0.y, o0.z, o0.w, o1.x, o1.y, o1.z, o1.w };
            #pragma unroll
            for (int j = 0; j < 8; ++j) {
                float val = t[i][j] + ov[j] + biv[j];
                t[i][j] = val;
                s1 += val;
                s2 += val * val;
            }
        }
        #pragma unroll
        for (int off = 1; off < 16; off <<= 1) {
            s1 += __shfl_xor(s1, off, 64);
            s2 += __shfl_xor(s2, off, 64);
        }
        if (valid) {
            float mean = s1 * (1.f / 128.f);
            float var = s2 * (1.f / 128.f) - mean * mean;
            float rstd = rsqrtf(var + 1e-5f);
            float res[8];
            #pragma unroll
            for (int j = 0; j < 8; ++j) {
                float nv = (t[i][j] - mean) * rstd * gv[j] + bv[j];
                float el = (nv > 0.f) ? nv : expm1f(nv);
                res[j] = el + Xt[c0 + j][(ty << 2) + i];
            }
            *(float4*)&y[(size_t)m * CC + c0]     = make_float4(res[0], res[1], res[2], res[3]);
            *(float4*)&y[(size_t)m * CC + c0 + 4] = make_float4(res[4], res[5], res[6], res[7]);
        }
    }
}

extern "C" void kernel_launch(void* const* d_in, const int* in_sizes, int n_in,
                              void* d_out, int out_size, void* d_ws, size_t ws_size,
                              hipStream_t stream) {
    const float* xu_in   = (const float*)d_in[0];
    const float* xi_in   = (const float*)d_in[1];
    const int*   ei_ui   = (const int*)d_in[2];
    const int*   ei_iu   = (const int*)d_in[3];
    const float* Wsrc_ui = (const float*)d_in[4];
    const float* Wdst_ui = (const float*)d_in[5];
    const float* asrc_ui = (const float*)d_in[6];
    const float* adst_ui = (const float*)d_in[7];
    const float* b_ui    = (const float*)d_in[8];
    const float* Wsrc_iu = (const float*)d_in[9];
    const float* Wdst_iu = (const float*)d_in[10];
    const float* asrc_iu = (const float*)d_in[11];
    const float* adst_iu = (const float*)d_in[12];
    const float* b_iu    = (const float*)d_in[13];
    const float* Ru      = (const float*)d_in[14];
    const float* Ri      = (const float*)d_in[15];
    const float* gu      = (const float*)d_in[16];
    const float* bu      = (const float*)d_in[17];
    const float* gi      = (const float*)d_in[18];
    const float* bi      = (const float*)d_in[19];
    float* out = (float*)d_out;          // [y_u (6.4M) | y_i (6.4M)]

    float* xu1 = out;
    float* xi1 = out + 6400000;

    // ---- workspace layout (~266 MB; ws_size >= 270.4 MB proven) ----
    float* ws = (float*)d_ws;
    size_t off = 0;
    ushort* aggT_hi = (ushort*)(ws + off); off += (size_t)NGRP * 128 * 128 / 2;   // 25.62M floats
    ushort* aggT_lo = (ushort*)(ws + off); off += (size_t)NGRP * 128 * 128 / 2;
    float* acc_i  = ws + off; off += 6400000;
    float* acc_u  = ws + off; off += 6400000;
    float* al_s_ui = ws + off; off += 400000;
    float* al_d_ui = ws + off; off += 400000;
    float* al_s_iu = ws + off; off += 400000;
    float* al_d_iu = ws + off; off += 400000;
    float* v4     = ws + off; off += 4096;
    ushort* wT_hi_ui = (ushort*)(ws + off); off += 65536;
    ushort* wT_lo_ui = (ushort*)(ws + off); off += 65536;
    ushort* wT_hi_iu = (ushort*)(ws + off); off += 65536;
    ushort* wT_lo_iu = (ushort*)(ws + off); off += 65536;
    int* ib = (int*)(ws + off);
    size_t ioff = 0;
    int* off_ui  = ib + ioff; ioff += NN + 1;
    int* off_iu  = ib + ioff; ioff += NN + 1;
    int* cur_ui  = ib + ioff; ioff += NN;
    int* cur_iu  = ib + ioff; ioff += NN;
    int* cnt_ui  = ib + ioff; ioff += NN;
    int* cnt_iu  = ib + ioff; ioff += NN;
    int* perm_ui = ib + ioff; ioff += NEDGE;
    int* perm_iu = ib + ioff; ioff += NEDGE;

    // ---- CSR build (once per call) ----
    hipMemsetAsync(cnt_ui, 0, NN * sizeof(int), stream);
    hipMemsetAsync(cnt_iu, 0, NN * sizeof(int), stream);
    const int ef_blocks = (2 * NEDGE + 255) / 256;
    csr_hist_kernel<<<ef_blocks, 256, 0, stream>>>(ei_ui, ei_iu, cnt_ui, cnt_iu);
    csr_scan_kernel<<<2, 1024, 0, stream>>>(cnt_ui, off_ui, cur_ui, cnt_iu, off_iu, cur_iu);
    csr_fill_kernel<<<ef_blocks, 256, 0, stream>>>(ei_ui, ei_iu, cur_ui, cur_iu, perm_ui, perm_iu);

    const int agg_blocks = (NN * 64 + 255) / 256;   // one wave per dst
    const int proj_blocks = (NN + 63) / 64;          // 782

    for (int l = 0; l < 2; ++l) {
        const float* xu = (l == 0) ? xu_in : xu1;
        const float* xi = (l == 0) ? xi_in : xi1;
        float* yu = (l == 0) ? xu1 : out;               // layer 1: in-place
        float* yi = (l == 0) ? xi1 : out + 6400000;

        fold_kernel<<<16, 256, 0, stream>>>(
            Wsrc_ui + (size_t)l * 131072, asrc_ui + (size_t)l * 1024,
            Wdst_ui + (size_t)l * 131072, adst_ui + (size_t)l * 1024,
            Wsrc_iu + (size_t)l * 131072, asrc_iu + (size_t)l * 1024,
            Wdst_iu + (size_t)l * 131072, adst_iu + (size_t)l * 1024, v4);

        al_kernel<<<dim3(1563, 4), 256, 0, stream>>>(xu, xi, v4,
                                                     al_s_ui, al_d_ui, al_s_iu, al_d_iu);

        wprep_kernel<<<dim3(512, 2), 256, 0, stream>>>(
            Wsrc_ui + (size_t)l * 131072, Wsrc_iu + (size_t)l * 131072,
            wT_hi_ui, wT_lo_ui, wT_hi_iu, wT_lo_iu);

        // ---- ui: src=users, dst=items -> acc_i ----
        agg_kernel<<<agg_blocks, 256, 0, stream>>>(ei_ui, off_ui, perm_ui,
                                                   al_s_ui, al_d_ui, xu, aggT_hi, aggT_lo);
        proj_mfma_kernel<<<proj_blocks, 256, 0, stream>>>(aggT_hi, aggT_lo,
                                                          wT_hi_ui, wT_lo_ui, acc_i);

        // ---- iu: src=items, dst=users -> acc_u ----
        agg_kernel<<<agg_blocks, 256, 0, stream>>>(ei_iu, off_iu, perm_iu,
                                                   al_s_iu, al_d_iu, xi, aggT_hi, aggT_lo);
        proj_mfma_kernel<<<proj_blocks, 256, 0, stream>>>(aggT_hi, aggT_lo,
                                                          wT_hi_iu, wT_lo_iu, acc_u);

        // ---- finalize (layer 1 in-place) ----
        finalize_kernel<<<782, 256, 0, stream>>>(acc_i, b_ui + (size_t)l * 128, xi,
                                                 Ri + (size_t)l * 16384, gi + (size_t)l * 128,
                                                 bi + (size_t)l * 128, yi, NI);
        finalize_kernel<<<782, 256, 0, stream>>>(acc_u, b_iu + (size_t)l * 128, xu,
                                                 Ru + (size_t)l * 16384, gu + (size_t)l * 128,
                                                 bu + (size_t)l * 128, yu, NU);
    }
}